// Round 6
// baseline (491.238 us; speedup 1.0000x reference)
//
#include <hip/hip_runtime.h>
#include <hip/hip_bf16.h>
#include <stdint.h>

typedef __attribute__((ext_vector_type(4))) float f32x4;
typedef __attribute__((ext_vector_type(8))) short short8;

#define DIM_S 4096
#define DIM_IN 1536
#define DIM_OUT 3072
#define NB 8
#define NORG 4

#define XB_ELEMS (NB * DIM_S * DIM_IN)      /* 50331648 */
#define WT_ELEMS (NORG * DIM_OUT * DIM_IN)  /* 18874368 */
#define WS_NEED ((size_t)(XB_ELEMS + WT_ELEMS) * 2)

__device__ __forceinline__ unsigned short f2bf(float f) {
    union { __hip_bfloat16 h; unsigned short u; } c;
    c.h = __float2bfloat16(f);
    return c.u;
}

__device__ __forceinline__ void gload16(const void* g, void* l) {
    __builtin_amdgcn_global_load_lds(
        (const __attribute__((address_space(1))) unsigned int*)g,
        (__attribute__((address_space(3))) unsigned int*)l, 16, 0, 0);
}

// ---------- pass 1a: x f32 -> bf16 ----------
__global__ __launch_bounds__(256) void cvt_x(const float* __restrict__ x,
                                             unsigned short* __restrict__ xb) {
    const int nchunk = XB_ELEMS / 8;
    for (int c = blockIdx.x * 256 + threadIdx.x; c < nchunk; c += gridDim.x * 256) {
        const float4 v0 = *reinterpret_cast<const float4*>(x + (size_t)c * 8);
        const float4 v1 = *reinterpret_cast<const float4*>(x + (size_t)c * 8 + 4);
        union { unsigned short u[8]; short8 v; } p;
        p.u[0] = f2bf(v0.x); p.u[1] = f2bf(v0.y); p.u[2] = f2bf(v0.z); p.u[3] = f2bf(v0.w);
        p.u[4] = f2bf(v1.x); p.u[5] = f2bf(v1.y); p.u[6] = f2bf(v1.z); p.u[7] = f2bf(v1.w);
        *reinterpret_cast<short8*>(xb + (size_t)c * 8) = p.v;
    }
}

// ---------- pass 1b: W [org][K][N] f32 -> W^T [org][N][K] bf16 ----------
__global__ __launch_bounds__(256) void cvt_wt(const float* __restrict__ w,
                                              unsigned short* __restrict__ wt) {
    __shared__ unsigned short T[64][68];
    const int bid = blockIdx.x;
    const int org = bid / (24 * 48);
    const int rem = bid % (24 * 48);
    const int k0 = (rem / 48) * 64;
    const int n0 = (rem % 48) * 64;
    const float* __restrict__ wp = w + (size_t)org * DIM_IN * DIM_OUT;
    unsigned short* __restrict__ op = wt + (size_t)org * DIM_OUT * DIM_IN;
    const int t = threadIdx.x;
    #pragma unroll
    for (int i = 0; i < 4; ++i) {
        const int c = t + 256 * i;
        const int kk = c >> 4, nq = (c & 15) * 4;
        const float4 v = *reinterpret_cast<const float4*>(
            wp + (size_t)(k0 + kk) * DIM_OUT + n0 + nq);
        ushort4 pv;
        pv.x = f2bf(v.x); pv.y = f2bf(v.y); pv.z = f2bf(v.z); pv.w = f2bf(v.w);
        *reinterpret_cast<ushort4*>(&T[kk][nq]) = pv;
    }
    __syncthreads();
    #pragma unroll
    for (int i = 0; i < 2; ++i) {
        const int c = t + 256 * i;
        const int n = c >> 3, k8 = (c & 7) * 8;
        union { unsigned short u[8]; short8 v; } p;
        #pragma unroll
        for (int j = 0; j < 8; ++j) p.u[j] = T[k8 + j][n];
        *reinterpret_cast<short8*>(op + (size_t)(n0 + n) * DIM_IN + k0 + k8) = p.v;
    }
}

// ---------- pass 2: 256x256 8-phase bf16 GEMM, FRAGMENT-MAJOR LDS ----------
// LDS slot (16 KB) holds one operand tile half (256 rows x 32 k) in MFMA
// fragment order: frag f (rows 16f..16f+15, the 32-k half) at f*1024 bytes;
// within a frag, lane l's 16 B chunk (row 16f+(l&15), k 8*(l>>4)) at l*16.
// ds_read_b128 is then a LINEAR wave read (zero bank conflicts); staging
// scatters via per-lane global addresses (gload_lds dest stays lane-linear).
// Slots: 0=A-k0, 1=A-k1, 2=B-k0, 3=B-k1. vmcnt(8) counted, never drained.
__global__ __launch_bounds__(512, 2) void mol_gemm_8p(
    const unsigned short* __restrict__ xb, const int* __restrict__ orgidx,
    const unsigned short* __restrict__ wt, const float* __restrict__ bias,
    float* __restrict__ out)
{
    __shared__ __align__(16) unsigned short LDS[2][4][8192];  // 128 KiB

    const int tid  = threadIdx.x;
    const int lane = tid & 63;
    const int wave = tid >> 6;
    const int wr = wave >> 2;      // 0..1  (M half)
    const int wc = wave & 3;       // 0..3  (N quarter)
    const int l15 = lane & 15;
    const int q16 = lane >> 4;

    // XCD-aware remap: 1536 blocks = 8 XCDs x 192; col-fastest; 1 batch/XCD.
    const int bid = blockIdx.x;
    const int id  = (bid & 7) * 192 + (bid >> 3);
    const int row0 = (id / 12) * 256;
    const int col0 = (id % 12) * 256;
    const int batch = row0 >> 12;
    const int org   = orgidx[batch];

    const unsigned short* __restrict__ Abase = xb + (size_t)row0 * DIM_IN;
    const unsigned short* __restrict__ Bbase =
        wt + (size_t)org * DIM_OUT * DIM_IN + (size_t)col0 * DIM_IN;

    // staging source: lane l of stage-op j fetches frag (m = wave + 8j)'s
    // chunk l: row 16m + l15, k-quad q16.
    const unsigned short* pA0 = Abase + (size_t)(16 * wave + l15) * DIM_IN + q16 * 8;
    const unsigned short* pA1 = pA0 + (size_t)128 * DIM_IN;
    const unsigned short* pB0 = Bbase + (size_t)(16 * wave + l15) * DIM_IN + q16 * 8;
    const unsigned short* pB1 = pB0 + (size_t)128 * DIM_IN;

    // LDS dest bases (elements): frag (wave) and frag (wave+8)
    const int d0 = wave * 512;
    const int d1 = 4096 + wave * 512;

    f32x4 acc[8][4] = {};
    short8 af4[4], bfr[4];

#define STG(buf, slot, p0, p1, kofs) do {                      \
        gload16((p0) + (kofs), &LDS[buf][slot][d0]);           \
        gload16((p1) + (kofs), &LDS[buf][slot][d1]);           \
    } while (0)

// A frags for this wave: m = wr*8 + mih*4 + i_  -> byte off m*1024 + lane*16
#define RD_A4(buf, kk, mih) do {                                            \
        const char* bA_ = (const char*)(&LDS[buf][kk][0])                   \
                          + (wr * 8 + (mih) * 4) * 1024 + lane * 16;        \
        _Pragma("unroll")                                                   \
        for (int i_ = 0; i_ < 4; ++i_)                                      \
            af4[i_] = *reinterpret_cast<const short8*>(bA_ + 1024 * i_);    \
    } while (0)

// B frags for this wave: n = wc*4 + i_
#define RD_B4(buf, kk) do {                                                 \
        const char* bB_ = (const char*)(&LDS[buf][2 + (kk)][0])             \
                          + (wc * 4) * 1024 + lane * 16;                    \
        _Pragma("unroll")                                                   \
        for (int i_ = 0; i_ < 4; ++i_)                                      \
            bfr[i_] = *reinterpret_cast<const short8*>(bB_ + 1024 * i_);    \
    } while (0)

#define MM(mih) do {                                                        \
        __builtin_amdgcn_s_setprio(1);                                      \
        _Pragma("unroll")                                                   \
        for (int i_ = 0; i_ < 4; ++i_) {                                    \
            _Pragma("unroll")                                               \
            for (int n_ = 0; n_ < 4; ++n_)                                  \
                acc[(mih)*4 + i_][n_] =                                     \
                    __builtin_amdgcn_mfma_f32_16x16x32_bf16(                \
                        af4[i_], bfr[n_], acc[(mih)*4 + i_][n_], 0, 0, 0);  \
        }                                                                   \
        __builtin_amdgcn_s_setprio(0);                                      \
    } while (0)

#define BAR  do { __builtin_amdgcn_s_barrier();                             \
                  asm volatile("" ::: "memory"); } while (0)
#define SB0  __builtin_amdgcn_sched_barrier(0)
#define WAIT8 asm volatile("s_waitcnt vmcnt(8)" ::: "memory")

    // ---- prologue: tile0 all slots + tile1 k0 ----
    STG(0, 0, pA0, pA1, 0);
    STG(0, 2, pB0, pB1, 0);
    STG(0, 1, pA0, pA1, 32);
    STG(0, 3, pB0, pB1, 32);
    STG(1, 0, pA0, pA1, 64);
    STG(1, 2, pB0, pB1, 64);
    WAIT8;                       // tile0-k0 landed
    BAR;

    int kA = 96, kB = 96;

    // Stage schedule per tile t (2 tiles ahead; race-free per R4 analysis):
    //   P1 -> A(t+1,k1), P2 -> B(t+1,k1), P3 -> A(t+2,k0), P4 -> B(t+2,k0);
    //   vmcnt(8) before end-barrier of P2/P4 only.
#define PHASE(buf, kk, mih, sbuf, sslot, pp0, pp1, kref, wait8) do {        \
        RD_A4(buf, kk, mih);                                                \
        if ((mih) == 0) RD_B4(buf, kk);                                     \
        STG(sbuf, sslot, pp0, pp1, kref);                                   \
        if (kref < 1504) kref += 32;                                        \
        BAR; SB0;                                                           \
        MM(mih);                                                            \
        if (wait8) WAIT8;                                                   \
        BAR;                                                                \
    } while (0)

#define TILE(buf, obuf) do {                                                \
        PHASE(buf, 0, 0, obuf, 1, pA0, pA1, kA, 0);                         \
        PHASE(buf, 0, 1, obuf, 3, pB0, pB1, kB, 1);                         \
        PHASE(buf, 1, 0, buf,  0, pA0, pA1, kA, 0);                         \
        PHASE(buf, 1, 1, buf,  2, pB0, pB1, kB, 1);                         \
    } while (0)

    #pragma unroll 1
    for (int i = 0; i < 12; ++i) {   // 24 K-tiles, 2 per iter
        TILE(0, 1);
        TILE(1, 0);
    }

    // ---- epilogue: bias + store f32 ----
    const float* __restrict__ bptr = bias + (size_t)org * DIM_OUT;
    const int crow = q16 * 4;
    const int ccol = l15;
    #pragma unroll
    for (int ni = 0; ni < 4; ++ni) {
        const int gc = col0 + wc * 64 + ni * 16 + ccol;
        const float bv = bptr[gc];
        #pragma unroll
        for (int mi = 0; mi < 8; ++mi) {
            const int gr = row0 + wr * 128 + mi * 16 + crow;
            #pragma unroll
            for (int r = 0; r < 4; ++r)
                out[(size_t)(gr + r) * DIM_OUT + gc] = acc[mi][ni][r] + bv;
        }
    }
#undef STG
#undef RD_A4
#undef RD_B4
#undef MM
#undef BAR
#undef SB0
#undef WAIT8
#undef PHASE
#undef TILE
}

// ---------- fallback (R2 kernel) if ws too small ----------
#define BM 128
#define BN 128
#define BK 32
#define LDK 40
union BF8 { unsigned short u[8]; short8 v; };

__global__ __launch_bounds__(256) void mol_gemm_fb(
    const float* __restrict__ x, const int* __restrict__ orgidx,
    const float* __restrict__ weight, const float* __restrict__ bias,
    float* __restrict__ out)
{
    __shared__ __align__(16) unsigned short Alds[2][BM][LDK];
    __shared__ __align__(16) unsigned short Blds[2][BN][LDK];

    const int tid  = threadIdx.x;
    const int lane = tid & 63;
    const int wave = tid >> 6;
    const int wr = wave >> 1, wc = wave & 1;

    const int bid = blockIdx.x;
    const int id  = (bid & 7) * 768 + (bid >> 3);
    const int row0 = (id / 24) * BM;
    const int col0 = (id % 24) * BN;

    const int batch = row0 / DIM_S;
    const int org   = orgidx[batch];
    const float* __restrict__ W = weight + (size_t)org * DIM_IN * DIM_OUT;

    f32x4 acc[4][4] = {};
    const int ar  = tid >> 2;
    const int ak8 = (tid & 3) * 8;
    const int bn  = tid & 127;
    const int bg0 = tid >> 7;
    const float* __restrict__ xbase = x + (size_t)row0 * DIM_IN;
    const float* __restrict__ wbase = W + col0 + bn;

    auto stage = [&](int buf, int k0) {
        #pragma unroll
        for (int i = 0; i < 2; ++i) {
            const int r = ar + 64 * i;
            const float* xp = xbase + (size_t)r * DIM_IN + k0 + ak8;
            const float4 v0 = *reinterpret_cast<const float4*>(xp);
            const float4 v1 = *reinterpret_cast<const float4*>(xp + 4);
            BF8 p;
            p.u[0] = f2bf(v0.x); p.u[1] = f2bf(v0.y);
            p.u[2] = f2bf(v0.z); p.u[3] = f2bf(v0.w);
            p.u[4] = f2bf(v1.x); p.u[5] = f2bf(v1.y);
            p.u[6] = f2bf(v1.z); p.u[7] = f2bf(v1.w);
            *reinterpret_cast<short8*>(&Alds[buf][r][ak8]) = p.v;
        }
        #pragma unroll
        for (int j = 0; j < 2; ++j) {
            const int g = bg0 + 2 * j;
            const float* wp = wbase + (size_t)(k0 + 8 * g) * DIM_OUT;
            BF8 p;
            #pragma unroll
            for (int r = 0; r < 8; ++r) p.u[r] = f2bf(wp[(size_t)r * DIM_OUT]);
            *reinterpret_cast<short8*>(&Blds[buf][bn][8 * g]) = p.v;
        }
    };

    stage(0, 0);
    const int nk = DIM_IN / BK;
    const int kq = (lane >> 4) * 8;
    const int lr = lane & 15;

    for (int t = 0; t < nk; ++t) {
        __syncthreads();
        const int cur = t & 1;
        if (t + 1 < nk) stage(cur ^ 1, (t + 1) * BK);
        short8 a[4], b[4];
        #pragma unroll
        for (int mi = 0; mi < 4; ++mi)
            a[mi] = *reinterpret_cast<const short8*>(&Alds[cur][wr * 64 + mi * 16 + lr][kq]);
        #pragma unroll
        for (int ni = 0; ni < 4; ++ni)
            b[ni] = *reinterpret_cast<const short8*>(&Blds[cur][wc * 64 + ni * 16 + lr][kq]);
        #pragma unroll
        for (int mi = 0; mi < 4; ++mi)
            #pragma unroll
            for (int ni = 0; ni < 4; ++ni)
                acc[mi][ni] = __builtin_amdgcn_mfma_f32_16x16x32_bf16(
                    a[mi], b[ni], acc[mi][ni], 0, 0, 0);
    }

    const float* __restrict__ bptr = bias + (size_t)org * DIM_OUT;
    const int crow = (lane >> 4) * 4;
    const int ccol = lane & 15;
    #pragma unroll
    for (int ni = 0; ni < 4; ++ni) {
        const int gc = col0 + wc * 64 + ni * 16 + ccol;
        const float bv = bptr[gc];
        #pragma unroll
        for (int mi = 0; mi < 4; ++mi) {
            const int gr = row0 + wr * 64 + mi * 16 + crow;
            #pragma unroll
            for (int r = 0; r < 4; ++r)
                out[(size_t)(gr + r) * DIM_OUT + gc] = acc[mi][ni][r] + bv;
        }
    }
}

extern "C" void kernel_launch(void* const* d_in, const int* in_sizes, int n_in,
                              void* d_out, int out_size, void* d_ws, size_t ws_size,
                              hipStream_t stream)
{
    const float* x      = (const float*)d_in[0];
    const int*   orgidx = (const int*)d_in[1];
    const float* weight = (const float*)d_in[2];
    const float* bias   = (const float*)d_in[3];
    float* out = (float*)d_out;

    if (ws_size >= WS_NEED) {
        unsigned short* xbp = (unsigned short*)d_ws;
        unsigned short* wtp = xbp + XB_ELEMS;
        cvt_x<<<dim3(2048), dim3(256), 0, stream>>>(x, xbp);
        cvt_wt<<<dim3(NORG * 24 * 48), dim3(256), 0, stream>>>(weight, wtp);
        mol_gemm_8p<<<dim3(1536), dim3(512), 0, stream>>>(xbp, orgidx, wtp, bias, out);
    } else {
        mol_gemm_fb<<<dim3(6144), dim3(256), 0, stream>>>(x, orgidx, weight, bias, out);
    }
}

// Round 7
// 435.281 us; speedup vs baseline: 1.1286x; 1.1286x over previous
//
#include <hip/hip_runtime.h>
#include <hip/hip_bf16.h>
#include <stdint.h>

typedef __attribute__((ext_vector_type(4))) float f32x4;
typedef __attribute__((ext_vector_type(8))) short short8;

#define DIM_S 4096
#define DIM_IN 1536
#define DIM_OUT 3072
#define NB 8
#define NORG 4

#define XB_ELEMS (NB * DIM_S * DIM_IN)      /* 50331648 */
#define WT_ELEMS (NORG * DIM_OUT * DIM_IN)  /* 18874368 */
#define WS_NEED ((size_t)(XB_ELEMS + WT_ELEMS) * 2)

__device__ __forceinline__ unsigned short f2bf(float f) {
    union { __hip_bfloat16 h; unsigned short u; } c;
    c.h = __float2bfloat16(f);
    return c.u;
}

__device__ __forceinline__ void gload16(const void* g, void* l) {
    __builtin_amdgcn_global_load_lds(
        (const __attribute__((address_space(1))) unsigned int*)g,
        (__attribute__((address_space(3))) unsigned int*)l, 16, 0, 0);
}

// ---------- pass 1a: x f32 -> bf16 ----------
__global__ __launch_bounds__(256) void cvt_x(const float* __restrict__ x,
                                             unsigned short* __restrict__ xb) {
    const int nchunk = XB_ELEMS / 8;
    for (int c = blockIdx.x * 256 + threadIdx.x; c < nchunk; c += gridDim.x * 256) {
        const float4 v0 = *reinterpret_cast<const float4*>(x + (size_t)c * 8);
        const float4 v1 = *reinterpret_cast<const float4*>(x + (size_t)c * 8 + 4);
        union { unsigned short u[8]; short8 v; } p;
        p.u[0] = f2bf(v0.x); p.u[1] = f2bf(v0.y); p.u[2] = f2bf(v0.z); p.u[3] = f2bf(v0.w);
        p.u[4] = f2bf(v1.x); p.u[5] = f2bf(v1.y); p.u[6] = f2bf(v1.z); p.u[7] = f2bf(v1.w);
        *reinterpret_cast<short8*>(xb + (size_t)c * 8) = p.v;
    }
}

// ---------- pass 1b: W [org][K][N] f32 -> W^T [org][N][K] bf16 ----------
__global__ __launch_bounds__(256) void cvt_wt(const float* __restrict__ w,
                                              unsigned short* __restrict__ wt) {
    __shared__ unsigned short T[64][68];
    const int bid = blockIdx.x;
    const int org = bid / (24 * 48);
    const int rem = bid % (24 * 48);
    const int k0 = (rem / 48) * 64;
    const int n0 = (rem % 48) * 64;
    const float* __restrict__ wp = w + (size_t)org * DIM_IN * DIM_OUT;
    unsigned short* __restrict__ op = wt + (size_t)org * DIM_OUT * DIM_IN;
    const int t = threadIdx.x;
    #pragma unroll
    for (int i = 0; i < 4; ++i) {
        const int c = t + 256 * i;
        const int kk = c >> 4, nq = (c & 15) * 4;
        const float4 v = *reinterpret_cast<const float4*>(
            wp + (size_t)(k0 + kk) * DIM_OUT + n0 + nq);
        ushort4 pv;
        pv.x = f2bf(v.x); pv.y = f2bf(v.y); pv.z = f2bf(v.z); pv.w = f2bf(v.w);
        *reinterpret_cast<ushort4*>(&T[kk][nq]) = pv;
    }
    __syncthreads();
    #pragma unroll
    for (int i = 0; i < 2; ++i) {
        const int c = t + 256 * i;
        const int n = c >> 3, k8 = (c & 7) * 8;
        union { unsigned short u[8]; short8 v; } p;
        #pragma unroll
        for (int j = 0; j < 8; ++j) p.u[j] = T[k8 + j][n];
        *reinterpret_cast<short8*>(op + (size_t)(n0 + n) * DIM_IN + k0 + k8) = p.v;
    }
}

// ---------- pass 2: 256x256 8-phase bf16 GEMM, st_16x32 swizzle ----------
// LDS slot = [256 rows][32 k] bf16 (stacked 1024B subtiles of 16 rows x 32k).
// m201 st_16x32 swizzle: byte ^= ((byte>>9)&1)<<5, i.e. physical k-quad
// p = q ^ (((row>>3)&1)<<1). Applied on the pre-swizzled global source
// (staging; keeps 64B row clusters for coalescing) and on the ds_read
// offset (both-sides involution, rule #21). gload_lds dest stays linear.
// Slots: 0=A-k0, 1=A-k1, 2=B-k0, 3=B-k1. vmcnt(8) counted, never drained.
__global__ __launch_bounds__(512, 2) void mol_gemm_8p(
    const unsigned short* __restrict__ xb, const int* __restrict__ orgidx,
    const unsigned short* __restrict__ wt, const float* __restrict__ bias,
    float* __restrict__ out)
{
    __shared__ __align__(16) unsigned short LDS[2][4][8192];  // 128 KiB

    const int tid  = threadIdx.x;
    const int lane = tid & 63;
    const int wave = tid >> 6;
    const int wr = wave >> 2;      // 0..1  (M half)
    const int wc = wave & 3;       // 0..3  (N quarter)
    const int l15 = lane & 15;
    const int q16 = lane >> 4;

    // XCD-aware remap: 1536 blocks = 8 XCDs x 192; col-fastest; 1 batch/XCD.
    const int bid = blockIdx.x;
    const int id  = (bid & 7) * 192 + (bid >> 3);
    const int row0 = (id / 12) * 256;
    const int col0 = (id % 12) * 256;
    const int batch = row0 >> 12;
    const int org   = orgidx[batch];

    const unsigned short* __restrict__ Abase = xb + (size_t)row0 * DIM_IN;
    const unsigned short* __restrict__ Bbase =
        wt + (size_t)org * DIM_OUT * DIM_IN + (size_t)col0 * DIM_IN;

    // staging source: chunk c = tid covers slot row r = tid>>2 (and r+128),
    // physical quad p = tid&3 -> logical quad q = p ^ swz(r),
    // swz(r) = ((r>>3)&1)<<1  (st_16x32). 4-lane clusters stay within one
    // 64B row segment -> full coalescing.
    const int rA = tid >> 2;
    const int qs = ((tid & 3) ^ (((tid >> 5) & 1) << 1)) * 8;
    const unsigned short* pA0 = Abase + (size_t)rA * DIM_IN + qs;
    const unsigned short* pA1 = Abase + (size_t)(128 + rA) * DIM_IN + qs;
    const unsigned short* pB0 = Bbase + (size_t)rA * DIM_IN + qs;
    const unsigned short* pB1 = Bbase + (size_t)(128 + rA) * DIM_IN + qs;

    const int d0 = wave * 512;
    const int d1 = 4096 + wave * 512;

    // ds_read byte offsets: row = (frag*16 + l15); bit3 of row = bit3 of l15.
    const int swb = ((l15 >> 3) & 1) << 1;
    const int offA0 = ((wr * 128 + l15) * 32 + ((q16 ^ swb) << 3)) * 2;
    const int offB0 = ((wc * 64  + l15) * 32 + ((q16 ^ swb) << 3)) * 2;

    f32x4 acc[8][4] = {};
    short8 af4[4], bfr[4];

#define STG(buf, slot, p0, p1, kofs) do {                      \
        gload16((p0) + (kofs), &LDS[buf][slot][d0]);           \
        gload16((p1) + (kofs), &LDS[buf][slot][d1]);           \
    } while (0)

#define RD_A4(buf, kk, mih) do {                                            \
        const char* bA_ = (const char*)(&LDS[buf][kk][0]) + offA0           \
                          + 4096 * (mih);                                   \
        _Pragma("unroll")                                                   \
        for (int i_ = 0; i_ < 4; ++i_)                                      \
            af4[i_] = *reinterpret_cast<const short8*>(bA_ + 1024 * i_);    \
    } while (0)

#define RD_B4(buf, kk) do {                                                 \
        const char* bB_ = (const char*)(&LDS[buf][2 + (kk)][0]) + offB0;    \
        _Pragma("unroll")                                                   \
        for (int i_ = 0; i_ < 4; ++i_)                                      \
            bfr[i_] = *reinterpret_cast<const short8*>(bB_ + 1024 * i_);    \
    } while (0)

#define MM(mih) do {                                                        \
        __builtin_amdgcn_s_setprio(1);                                      \
        _Pragma("unroll")                                                   \
        for (int i_ = 0; i_ < 4; ++i_) {                                    \
            _Pragma("unroll")                                               \
            for (int n_ = 0; n_ < 4; ++n_)                                  \
                acc[(mih)*4 + i_][n_] =                                     \
                    __builtin_amdgcn_mfma_f32_16x16x32_bf16(                \
                        af4[i_], bfr[n_], acc[(mih)*4 + i_][n_], 0, 0, 0);  \
        }                                                                   \
        __builtin_amdgcn_s_setprio(0);                                      \
    } while (0)

#define BAR  do { __builtin_amdgcn_s_barrier();                             \
                  asm volatile("" ::: "memory"); } while (0)
#define SB0  __builtin_amdgcn_sched_barrier(0)
#define WAIT8 asm volatile("s_waitcnt vmcnt(8)" ::: "memory")

    // ---- prologue: tile0 all slots + tile1 k0 ----
    STG(0, 0, pA0, pA1, 0);
    STG(0, 2, pB0, pB1, 0);
    STG(0, 1, pA0, pA1, 32);
    STG(0, 3, pB0, pB1, 32);
    STG(1, 0, pA0, pA1, 64);
    STG(1, 2, pB0, pB1, 64);
    WAIT8;                       // tile0-k0 landed
    BAR;

    int kA = 96, kB = 96;

    // Stage schedule per tile t (2 tiles ahead; verified race-free R4/R6):
    //   P1 -> A(t+1,k1), P2 -> B(t+1,k1), P3 -> A(t+2,k0), P4 -> B(t+2,k0);
    //   vmcnt(8) before end-barrier of P2/P4 only.
#define PHASE(buf, kk, mih, sbuf, sslot, pp0, pp1, kref, wait8) do {        \
        RD_A4(buf, kk, mih);                                                \
        if ((mih) == 0) RD_B4(buf, kk);                                     \
        STG(sbuf, sslot, pp0, pp1, kref);                                   \
        if (kref < 1504) kref += 32;                                        \
        BAR; SB0;                                                           \
        MM(mih);                                                            \
        if (wait8) WAIT8;                                                   \
        BAR;                                                                \
    } while (0)

#define TILE(buf, obuf) do {                                                \
        PHASE(buf, 0, 0, obuf, 1, pA0, pA1, kA, 0);                         \
        PHASE(buf, 0, 1, obuf, 3, pB0, pB1, kB, 1);                         \
        PHASE(buf, 1, 0, buf,  0, pA0, pA1, kA, 0);                         \
        PHASE(buf, 1, 1, buf,  2, pB0, pB1, kB, 1);                         \
    } while (0)

    #pragma unroll 1
    for (int i = 0; i < 12; ++i) {   // 24 K-tiles, 2 per iter
        TILE(0, 1);
        TILE(1, 0);
    }

    // ---- epilogue: bias + store f32 ----
    const float* __restrict__ bptr = bias + (size_t)org * DIM_OUT;
    const int crow = q16 * 4;
    const int ccol = l15;
    #pragma unroll
    for (int ni = 0; ni < 4; ++ni) {
        const int gc = col0 + wc * 64 + ni * 16 + ccol;
        const float bv = bptr[gc];
        #pragma unroll
        for (int mi = 0; mi < 8; ++mi) {
            const int gr = row0 + wr * 128 + mi * 16 + crow;
            #pragma unroll
            for (int r = 0; r < 4; ++r)
                out[(size_t)(gr + r) * DIM_OUT + gc] = acc[mi][ni][r] + bv;
        }
    }
#undef STG
#undef RD_A4
#undef RD_B4
#undef MM
#undef BAR
#undef SB0
#undef WAIT8
#undef PHASE
#undef TILE
}

// ---------- fallback (R2 kernel) if ws too small ----------
#define BM 128
#define BN 128
#define BK 32
#define LDK 40
union BF8 { unsigned short u[8]; short8 v; };

__global__ __launch_bounds__(256) void mol_gemm_fb(
    const float* __restrict__ x, const int* __restrict__ orgidx,
    const float* __restrict__ weight, const float* __restrict__ bias,
    float* __restrict__ out)
{
    __shared__ __align__(16) unsigned short Alds[2][BM][LDK];
    __shared__ __align__(16) unsigned short Blds[2][BN][LDK];

    const int tid  = threadIdx.x;
    const int lane = tid & 63;
    const int wave = tid >> 6;
    const int wr = wave >> 1, wc = wave & 1;

    const int bid = blockIdx.x;
    const int id  = (bid & 7) * 768 + (bid >> 3);
    const int row0 = (id / 24) * BM;
    const int col0 = (id % 24) * BN;

    const int batch = row0 / DIM_S;
    const int org   = orgidx[batch];
    const float* __restrict__ W = weight + (size_t)org * DIM_IN * DIM_OUT;

    f32x4 acc[4][4] = {};
    const int ar  = tid >> 2;
    const int ak8 = (tid & 3) * 8;
    const int bn  = tid & 127;
    const int bg0 = tid >> 7;
    const float* __restrict__ xbase = x + (size_t)row0 * DIM_IN;
    const float* __restrict__ wbase = W + col0 + bn;

    auto stage = [&](int buf, int k0) {
        #pragma unroll
        for (int i = 0; i < 2; ++i) {
            const int r = ar + 64 * i;
            const float* xp = xbase + (size_t)r * DIM_IN + k0 + ak8;
            const float4 v0 = *reinterpret_cast<const float4*>(xp);
            const float4 v1 = *reinterpret_cast<const float4*>(xp + 4);
            BF8 p;
            p.u[0] = f2bf(v0.x); p.u[1] = f2bf(v0.y);
            p.u[2] = f2bf(v0.z); p.u[3] = f2bf(v0.w);
            p.u[4] = f2bf(v1.x); p.u[5] = f2bf(v1.y);
            p.u[6] = f2bf(v1.z); p.u[7] = f2bf(v1.w);
            *reinterpret_cast<short8*>(&Alds[buf][r][ak8]) = p.v;
        }
        #pragma unroll
        for (int j = 0; j < 2; ++j) {
            const int g = bg0 + 2 * j;
            const float* wp = wbase + (size_t)(k0 + 8 * g) * DIM_OUT;
            BF8 p;
            #pragma unroll
            for (int r = 0; r < 8; ++r) p.u[r] = f2bf(wp[(size_t)r * DIM_OUT]);
            *reinterpret_cast<short8*>(&Blds[buf][bn][8 * g]) = p.v;
        }
    };

    stage(0, 0);
    const int nk = DIM_IN / BK;
    const int kq = (lane >> 4) * 8;
    const int lr = lane & 15;

    for (int t = 0; t < nk; ++t) {
        __syncthreads();
        const int cur = t & 1;
        if (t + 1 < nk) stage(cur ^ 1, (t + 1) * BK);
        short8 a[4], b[4];
        #pragma unroll
        for (int mi = 0; mi < 4; ++mi)
            a[mi] = *reinterpret_cast<const short8*>(&Alds[cur][wr * 64 + mi * 16 + lr][kq]);
        #pragma unroll
        for (int ni = 0; ni < 4; ++ni)
            b[ni] = *reinterpret_cast<const short8*>(&Blds[cur][wc * 64 + ni * 16 + lr][kq]);
        #pragma unroll
        for (int mi = 0; mi < 4; ++mi)
            #pragma unroll
            for (int ni = 0; ni < 4; ++ni)
                acc[mi][ni] = __builtin_amdgcn_mfma_f32_16x16x32_bf16(
                    a[mi], b[ni], acc[mi][ni], 0, 0, 0);
    }

    const float* __restrict__ bptr = bias + (size_t)org * DIM_OUT;
    const int crow = (lane >> 4) * 4;
    const int ccol = lane & 15;
    #pragma unroll
    for (int ni = 0; ni < 4; ++ni) {
        const int gc = col0 + wc * 64 + ni * 16 + ccol;
        const float bv = bptr[gc];
        #pragma unroll
        for (int mi = 0; mi < 4; ++mi) {
            const int gr = row0 + wr * 64 + mi * 16 + crow;
            #pragma unroll
            for (int r = 0; r < 4; ++r)
                out[(size_t)(gr + r) * DIM_OUT + gc] = acc[mi][ni][r] + bv;
        }
    }
}

extern "C" void kernel_launch(void* const* d_in, const int* in_sizes, int n_in,
                              void* d_out, int out_size, void* d_ws, size_t ws_size,
                              hipStream_t stream)
{
    const float* x      = (const float*)d_in[0];
    const int*   orgidx = (const int*)d_in[1];
    const float* weight = (const float*)d_in[2];
    const float* bias   = (const float*)d_in[3];
    float* out = (float*)d_out;

    if (ws_size >= WS_NEED) {
        unsigned short* xbp = (unsigned short*)d_ws;
        unsigned short* wtp = xbp + XB_ELEMS;
        cvt_x<<<dim3(2048), dim3(256), 0, stream>>>(x, xbp);
        cvt_wt<<<dim3(NORG * 24 * 48), dim3(256), 0, stream>>>(weight, wtp);
        mol_gemm_8p<<<dim3(1536), dim3(512), 0, stream>>>(xbp, orgidx, wtp, bias, out);
    } else {
        mol_gemm_fb<<<dim3(6144), dim3(256), 0, stream>>>(x, orgidx, weight, bias, out);
    }
}

// Round 8
// 429.020 us; speedup vs baseline: 1.1450x; 1.0146x over previous
//
#include <hip/hip_runtime.h>
#include <hip/hip_bf16.h>
#include <stdint.h>

typedef __attribute__((ext_vector_type(4))) float f32x4;
typedef __attribute__((ext_vector_type(8))) short short8;

#define DIM_S 4096
#define DIM_IN 1536
#define DIM_OUT 3072
#define NB 8
#define NORG 4

#define XB_ELEMS (NB * DIM_S * DIM_IN)      /* 50331648 */
#define WT_ELEMS (NORG * DIM_OUT * DIM_IN)  /* 18874368 */
#define WS_NEED ((size_t)(XB_ELEMS + WT_ELEMS) * 2)

__device__ __forceinline__ unsigned short f2bf(float f) {
    union { __hip_bfloat16 h; unsigned short u; } c;
    c.h = __float2bfloat16(f);
    return c.u;
}

__device__ __forceinline__ void gload16(const void* g, void* l) {
    __builtin_amdgcn_global_load_lds(
        (const __attribute__((address_space(1))) unsigned int*)g,
        (__attribute__((address_space(3))) unsigned int*)l, 16, 0, 0);
}

// ---------- pass 1a: x f32 -> bf16 ----------
__global__ __launch_bounds__(256) void cvt_x(const float* __restrict__ x,
                                             unsigned short* __restrict__ xb) {
    const int nchunk = XB_ELEMS / 8;
    for (int c = blockIdx.x * 256 + threadIdx.x; c < nchunk; c += gridDim.x * 256) {
        const float4 v0 = *reinterpret_cast<const float4*>(x + (size_t)c * 8);
        const float4 v1 = *reinterpret_cast<const float4*>(x + (size_t)c * 8 + 4);
        union { unsigned short u[8]; short8 v; } p;
        p.u[0] = f2bf(v0.x); p.u[1] = f2bf(v0.y); p.u[2] = f2bf(v0.z); p.u[3] = f2bf(v0.w);
        p.u[4] = f2bf(v1.x); p.u[5] = f2bf(v1.y); p.u[6] = f2bf(v1.z); p.u[7] = f2bf(v1.w);
        *reinterpret_cast<short8*>(xb + (size_t)c * 8) = p.v;
    }
}

// ---------- pass 1b: W [org][K][N] f32 -> W^T [org][N][K] bf16 ----------
__global__ __launch_bounds__(256) void cvt_wt(const float* __restrict__ w,
                                              unsigned short* __restrict__ wt) {
    __shared__ unsigned short T[64][68];
    const int bid = blockIdx.x;
    const int org = bid / (24 * 48);
    const int rem = bid % (24 * 48);
    const int k0 = (rem / 48) * 64;
    const int n0 = (rem % 48) * 64;
    const float* __restrict__ wp = w + (size_t)org * DIM_IN * DIM_OUT;
    unsigned short* __restrict__ op = wt + (size_t)org * DIM_OUT * DIM_IN;
    const int t = threadIdx.x;
    #pragma unroll
    for (int i = 0; i < 4; ++i) {
        const int c = t + 256 * i;
        const int kk = c >> 4, nq = (c & 15) * 4;
        const float4 v = *reinterpret_cast<const float4*>(
            wp + (size_t)(k0 + kk) * DIM_OUT + n0 + nq);
        ushort4 pv;
        pv.x = f2bf(v.x); pv.y = f2bf(v.y); pv.z = f2bf(v.z); pv.w = f2bf(v.w);
        *reinterpret_cast<ushort4*>(&T[kk][nq]) = pv;
    }
    __syncthreads();
    #pragma unroll
    for (int i = 0; i < 2; ++i) {
        const int c = t + 256 * i;
        const int n = c >> 3, k8 = (c & 7) * 8;
        union { unsigned short u[8]; short8 v; } p;
        #pragma unroll
        for (int j = 0; j < 8; ++j) p.u[j] = T[k8 + j][n];
        *reinterpret_cast<short8*>(op + (size_t)(n0 + n) * DIM_IN + k0 + k8) = p.v;
    }
}

// ---------- pass 2: 256x256 8-phase GEMM + 1-phase register prefetch ----------
// LDS slot = [256 rows][32 k] bf16, st_16x32 swizzle (R7, conflicts=0).
// Slots: 0=A-k0, 1=A-k1, 2=B-k0, 3=B-k1 per buf. Staging schedule identical
// to R7 (race-free). NEW: fragment ds_reads are issued one phase ahead into
// alternating register sets, so MFMA(p) overlaps the LDS reads for p+1.
// vmcnt(4) at even phases (tightened from 8) makes every prefetched slot
// provably landed >=1 barrier before its read-issue. One barrier per phase.
__global__ __launch_bounds__(512, 2) void mol_gemm_8p(
    const unsigned short* __restrict__ xb, const int* __restrict__ orgidx,
    const unsigned short* __restrict__ wt, const float* __restrict__ bias,
    float* __restrict__ out)
{
    __shared__ __align__(16) unsigned short LDS[2][4][8192];  // 128 KiB

    const int tid  = threadIdx.x;
    const int lane = tid & 63;
    const int wave = tid >> 6;
    const int wr = wave >> 2;      // 0..1  (M half)
    const int wc = wave & 3;       // 0..3  (N quarter)
    const int l15 = lane & 15;
    const int q16 = lane >> 4;

    // XCD-aware remap: 1536 blocks = 8 XCDs x 192; col-fastest; 1 batch/XCD.
    const int bid = blockIdx.x;
    const int id  = (bid & 7) * 192 + (bid >> 3);
    const int row0 = (id / 12) * 256;
    const int col0 = (id % 12) * 256;
    const int batch = row0 >> 12;
    const int org   = orgidx[batch];

    const unsigned short* __restrict__ Abase = xb + (size_t)row0 * DIM_IN;
    const unsigned short* __restrict__ Bbase =
        wt + (size_t)org * DIM_OUT * DIM_IN + (size_t)col0 * DIM_IN;

    // staging source (pre-swizzled global k-quad, st_16x32)
    const int rA = tid >> 2;
    const int qs = ((tid & 3) ^ (((tid >> 5) & 1) << 1)) * 8;
    const unsigned short* pA0 = Abase + (size_t)rA * DIM_IN + qs;
    const unsigned short* pA1 = Abase + (size_t)(128 + rA) * DIM_IN + qs;
    const unsigned short* pB0 = Bbase + (size_t)rA * DIM_IN + qs;
    const unsigned short* pB1 = Bbase + (size_t)(128 + rA) * DIM_IN + qs;

    const int d0 = wave * 512;
    const int d1 = 4096 + wave * 512;

    // ds_read byte offsets (swizzled)
    const int swb = ((l15 >> 3) & 1) << 1;
    const int offA0 = ((wr * 128 + l15) * 32 + ((q16 ^ swb) << 3)) * 2;
    const int offB0 = ((wc * 64  + l15) * 32 + ((q16 ^ swb) << 3)) * 2;

    f32x4 acc[8][4] = {};
    short8 af[2][4], bfr[2][4];

#define STG(buf, slot, p0, p1, kofs) do {                      \
        gload16((p0) + (kofs), &LDS[buf][slot][d0]);           \
        gload16((p1) + (kofs), &LDS[buf][slot][d1]);           \
    } while (0)

#define RD_A4(dst, buf, kk, mih) do {                                       \
        const char* pA_ = (const char*)(&LDS[buf][kk][0]) + offA0           \
                          + 4096 * (mih);                                   \
        _Pragma("unroll")                                                   \
        for (int i_ = 0; i_ < 4; ++i_)                                      \
            af[dst][i_] = *reinterpret_cast<const short8*>(pA_ + 1024*i_);  \
    } while (0)

#define RD_B4(dst, buf, kk) do {                                            \
        const char* pB_ = (const char*)(&LDS[buf][2 + (kk)][0]) + offB0;    \
        _Pragma("unroll")                                                   \
        for (int i_ = 0; i_ < 4; ++i_)                                      \
            bfr[dst][i_] = *reinterpret_cast<const short8*>(pB_ + 1024*i_); \
    } while (0)

#define MM(ca, cb, mih) do {                                                \
        __builtin_amdgcn_s_setprio(1);                                      \
        _Pragma("unroll")                                                   \
        for (int i_ = 0; i_ < 4; ++i_) {                                    \
            _Pragma("unroll")                                               \
            for (int n_ = 0; n_ < 4; ++n_)                                  \
                acc[(mih)*4 + i_][n_] =                                     \
                    __builtin_amdgcn_mfma_f32_16x16x32_bf16(                \
                        af[ca][i_], bfr[cb][n_],                            \
                        acc[(mih)*4 + i_][n_], 0, 0, 0);                    \
        }                                                                   \
        __builtin_amdgcn_s_setprio(0);                                      \
    } while (0)

#define BAR  do { __builtin_amdgcn_s_barrier();                             \
                  asm volatile("" ::: "memory"); } while (0)
#define WAIT4 asm volatile("s_waitcnt vmcnt(4)" ::: "memory")
#define WAIT8 asm volatile("s_waitcnt vmcnt(8)" ::: "memory")
#define KADV(k) do { if ((k) < 1504) (k) += 32; } while (0)

    // ---- prologue: tile0 all slots + tile1 k0; preload P1 fragments ----
    STG(0, 0, pA0, pA1, 0);
    STG(0, 2, pB0, pB1, 0);
    STG(0, 1, pA0, pA1, 32);
    STG(0, 3, pB0, pB1, 32);
    STG(1, 0, pA0, pA1, 64);
    STG(1, 2, pB0, pB1, 64);
    WAIT8;                       // oldest 4 (tile0-k0 A,B) landed
    BAR;
    RD_A4(0, 0, 0, 0);           // af0 <- A(t0,k0,mih0)
    RD_B4(0, 0, 0);              // bf0 <- B(t0,k0)

    int kA = 96, kB = 96;

    // 8 phases / 2 K-tiles (T even in buf0, T+1 in buf1).
    // Phase p: [STG(p) ; PREF-RD(p+1) -> alt set ; MFMA(p) <- cur set ;
    //           (WAIT4 at even p) ; BAR]
    // STG targets and PREF sources verified disjoint for every phase;
    // vmcnt(4) at even phases covers every PREF's staging dependency.
#define TILE2() do {                                                        \
  /*P1*/ STG(1,1,pA0,pA1,kA); KADV(kA); RD_A4(1, 0,0,1);                    \
         MM(0,0,0);                 BAR;                                    \
  /*P2*/ STG(1,3,pB0,pB1,kB); KADV(kB); RD_A4(0, 0,1,0); RD_B4(1, 0,1);    \
         MM(1,0,1);          WAIT4; BAR;                                    \
  /*P3*/ STG(0,0,pA0,pA1,kA); KADV(kA); RD_A4(1, 0,1,1);                    \
         MM(0,1,0);                 BAR;                                    \
  /*P4*/ STG(0,2,pB0,pB1,kB); KADV(kB); RD_A4(0, 1,0,0); RD_B4(0, 1,0);    \
         MM(1,1,1);          WAIT4; BAR;                                    \
  /*P5*/ STG(0,1,pA0,pA1,kA); KADV(kA); RD_A4(1, 1,0,1);                    \
         MM(0,0,0);                 BAR;                                    \
  /*P6*/ STG(0,3,pB0,pB1,kB); KADV(kB); RD_A4(0, 1,1,0); RD_B4(1, 1,1);    \
         MM(1,0,1);          WAIT4; BAR;                                    \
  /*P7*/ STG(1,0,pA0,pA1,kA); KADV(kA); RD_A4(1, 1,1,1);                    \
         MM(0,1,0);                 BAR;                                    \
  /*P8*/ STG(1,2,pB0,pB1,kB); KADV(kB); RD_A4(0, 0,0,0); RD_B4(0, 0,0);    \
         MM(1,1,1);          WAIT4; BAR;                                    \
} while (0)

    #pragma unroll 1
    for (int i = 0; i < 12; ++i) {   // 24 K-tiles, 2 per TILE2
        TILE2();
    }

    // ---- epilogue: bias + store f32 ----
    const float* __restrict__ bptr = bias + (size_t)org * DIM_OUT;
    const int crow = q16 * 4;
    const int ccol = l15;
    #pragma unroll
    for (int ni = 0; ni < 4; ++ni) {
        const int gc = col0 + wc * 64 + ni * 16 + ccol;
        const float bv = bptr[gc];
        #pragma unroll
        for (int mi = 0; mi < 8; ++mi) {
            const int gr = row0 + wr * 128 + mi * 16 + crow;
            #pragma unroll
            for (int r = 0; r < 4; ++r)
                out[(size_t)(gr + r) * DIM_OUT + gc] = acc[mi][ni][r] + bv;
        }
    }
#undef STG
#undef RD_A4
#undef RD_B4
#undef MM
#undef BAR
#undef WAIT4
#undef WAIT8
#undef KADV
#undef TILE2
}

// ---------- fallback (R2 kernel) if ws too small ----------
#define BM 128
#define BN 128
#define BK 32
#define LDK 40
union BF8 { unsigned short u[8]; short8 v; };

__global__ __launch_bounds__(256) void mol_gemm_fb(
    const float* __restrict__ x, const int* __restrict__ orgidx,
    const float* __restrict__ weight, const float* __restrict__ bias,
    float* __restrict__ out)
{
    __shared__ __align__(16) unsigned short Alds[2][BM][LDK];
    __shared__ __align__(16) unsigned short Blds[2][BN][LDK];

    const int tid  = threadIdx.x;
    const int lane = tid & 63;
    const int wave = tid >> 6;
    const int wr = wave >> 1, wc = wave & 1;

    const int bid = blockIdx.x;
    const int id  = (bid & 7) * 768 + (bid >> 3);
    const int row0 = (id / 24) * BM;
    const int col0 = (id % 24) * BN;

    const int batch = row0 / DIM_S;
    const int org   = orgidx[batch];
    const float* __restrict__ W = weight + (size_t)org * DIM_IN * DIM_OUT;

    f32x4 acc[4][4] = {};
    const int ar  = tid >> 2;
    const int ak8 = (tid & 3) * 8;
    const int bn  = tid & 127;
    const int bg0 = tid >> 7;
    const float* __restrict__ xbase = x + (size_t)row0 * DIM_IN;
    const float* __restrict__ wbase = W + col0 + bn;

    auto stage = [&](int buf, int k0) {
        #pragma unroll
        for (int i = 0; i < 2; ++i) {
            const int r = ar + 64 * i;
            const float* xp = xbase + (size_t)r * DIM_IN + k0 + ak8;
            const float4 v0 = *reinterpret_cast<const float4*>(xp);
            const float4 v1 = *reinterpret_cast<const float4*>(xp + 4);
            BF8 p;
            p.u[0] = f2bf(v0.x); p.u[1] = f2bf(v0.y);
            p.u[2] = f2bf(v0.z); p.u[3] = f2bf(v0.w);
            p.u[4] = f2bf(v1.x); p.u[5] = f2bf(v1.y);
            p.u[6] = f2bf(v1.z); p.u[7] = f2bf(v1.w);
            *reinterpret_cast<short8*>(&Alds[buf][r][ak8]) = p.v;
        }
        #pragma unroll
        for (int j = 0; j < 2; ++j) {
            const int g = bg0 + 2 * j;
            const float* wp = wbase + (size_t)(k0 + 8 * g) * DIM_OUT;
            BF8 p;
            #pragma unroll
            for (int r = 0; r < 8; ++r) p.u[r] = f2bf(wp[(size_t)r * DIM_OUT]);
            *reinterpret_cast<short8*>(&Blds[buf][bn][8 * g]) = p.v;
        }
    };

    stage(0, 0);
    const int nk = DIM_IN / BK;
    const int kq = (lane >> 4) * 8;
    const int lr = lane & 15;

    for (int t = 0; t < nk; ++t) {
        __syncthreads();
        const int cur = t & 1;
        if (t + 1 < nk) stage(cur ^ 1, (t + 1) * BK);
        short8 a[4], b[4];
        #pragma unroll
        for (int mi = 0; mi < 4; ++mi)
            a[mi] = *reinterpret_cast<const short8*>(&Alds[cur][wr * 64 + mi * 16 + lr][kq]);
        #pragma unroll
        for (int ni = 0; ni < 4; ++ni)
            b[ni] = *reinterpret_cast<const short8*>(&Blds[cur][wc * 64 + ni * 16 + lr][kq]);
        #pragma unroll
        for (int mi = 0; mi < 4; ++mi)
            #pragma unroll
            for (int ni = 0; ni < 4; ++ni)
                acc[mi][ni] = __builtin_amdgcn_mfma_f32_16x16x32_bf16(
                    a[mi], b[ni], acc[mi][ni], 0, 0, 0);
    }

    const float* __restrict__ bptr = bias + (size_t)org * DIM_OUT;
    const int crow = (lane >> 4) * 4;
    const int ccol = lane & 15;
    #pragma unroll
    for (int ni = 0; ni < 4; ++ni) {
        const int gc = col0 + wc * 64 + ni * 16 + ccol;
        const float bv = bptr[gc];
        #pragma unroll
        for (int mi = 0; mi < 4; ++mi) {
            const int gr = row0 + wr * 64 + mi * 16 + crow;
            #pragma unroll
            for (int r = 0; r < 4; ++r)
                out[(size_t)(gr + r) * DIM_OUT + gc] = acc[mi][ni][r] + bv;
        }
    }
}

extern "C" void kernel_launch(void* const* d_in, const int* in_sizes, int n_in,
                              void* d_out, int out_size, void* d_ws, size_t ws_size,
                              hipStream_t stream)
{
    const float* x      = (const float*)d_in[0];
    const int*   orgidx = (const int*)d_in[1];
    const float* weight = (const float*)d_in[2];
    const float* bias   = (const float*)d_in[3];
    float* out = (float*)d_out;

    if (ws_size >= WS_NEED) {
        unsigned short* xbp = (unsigned short*)d_ws;
        unsigned short* wtp = xbp + XB_ELEMS;
        cvt_x<<<dim3(2048), dim3(256), 0, stream>>>(x, xbp);
        cvt_wt<<<dim3(NORG * 24 * 48), dim3(256), 0, stream>>>(weight, wtp);
        mol_gemm_8p<<<dim3(1536), dim3(512), 0, stream>>>(xbp, orgidx, wtp, bias, out);
    } else {
        mol_gemm_fb<<<dim3(6144), dim3(256), 0, stream>>>(x, orgidx, weight, bias, out);
    }
}